// Round 18
// baseline (508.516 us; speedup 1.0000x reference)
//
#include <hip/hip_runtime.h>

typedef unsigned short ushort_t;
typedef unsigned char uchar_t;
typedef unsigned int uint32;
typedef __attribute__((ext_vector_type(8))) short short8;
typedef __attribute__((ext_vector_type(4))) float f32x4;
typedef __attribute__((ext_vector_type(2))) float f32x2;

#define HID 256
#define MI 128
// p1 is pre-scaled by ALPHA = 2/ln2, so sim MFMA output = cos*2/ln2 and
// exp(cos/T) = exp2(acc) directly. Edge ln-logit: s = 2*cos = d * ln2.
#define ALPHA 2.8853900817779268f
#define LN2F 0.69314718055994531f

__device__ __forceinline__ float bflo(uint32 u) { return __uint_as_float(u << 16); }
__device__ __forceinline__ float bfhi(uint32 u) { return __uint_as_float(u & 0xffff0000u); }
__device__ __forceinline__ ushort_t f2bf(float f) {
  uint32 u = __float_as_uint(f);
  u += 0x7fffu + ((u >> 16) & 1u);   // RNE
  return (ushort_t)(u >> 16);
}

// ---------------------------------------------------------------------------
// Kernel 1 (prep fused, r13): p = l2norm(relu(h @ W + b)).
// Outputs BOTH bf16 (p1b/p2b, edge logits) and fp8 e4m3 (p1f8/p2f8, sim
// row/col sums). W staged to 64 KB LDS bf16 W^T. UNCHANGED from r15/r17.
// ---------------------------------------------------------------------------
__global__ __launch_bounds__(256) void proj_kernel(
    const float* __restrict__ h1, const float* __restrict__ h2,
    const float* __restrict__ W, const float* __restrict__ b,
    ushort_t* __restrict__ p1b, ushort_t* __restrict__ p2b,
    uchar_t* __restrict__ p1f8, uchar_t* __restrict__ p2f8,
    float* __restrict__ fbase, int nz, float* __restrict__ out, int n)
{
  __shared__ __align__(16) unsigned char wt[65536];   // 128 x 256 bf16 W^T
  int t = threadIdx.x;
  int lane = t & 63, w = t >> 6;
  int lr = lane & 15, lg = lane >> 4;
  long R0 = (long)blockIdx.x * 64;
  const float* src = (R0 < n) ? (h1 + R0 * HID) : (h2 + (R0 - n) * HID);
  ushort_t* dst = (R0 < n) ? (p1b + R0 * MI) : (p2b + (R0 - n) * MI);
  uchar_t* dst8 = (R0 < n) ? (p1f8 + R0 * MI) : (p2f8 + (R0 - n) * MI);
  float scale = (R0 < n) ? ALPHA : 1.0f;

  // ---- fbase zero slice (prep work, disjoint per block) ----
  {
    int base = blockIdx.x * 224;        // 512 * 224 = 114688 = 7n
    if (t < 224 && base + t < nz) fbase[base + t] = 0.f;
    if (blockIdx.x == 0 && t == 0) out[0] = 0.f;
  }

  // ---- Stage W -> LDS W^T (bf16, swizzled). 32 float4 per thread. ----
  #pragma unroll
  for (int i = 0; i < 32; ++i) {
    int idx4 = i * 1024 + t * 4;        // 4 consecutive ncol, same k
    float4 v = *(const float4*)(W + idx4);
    int k = idx4 >> 7, nc0 = idx4 & 127;
    int g = k >> 3, klo = (k & 7) * 2;
    #pragma unroll
    for (int j = 0; j < 4; ++j) {
      int nc = nc0 + j;
      float f = (j == 0) ? v.x : (j == 1) ? v.y : (j == 2) ? v.z : v.w;
      *(ushort_t*)(wt + nc * 512 + ((g ^ (nc & 31)) << 4) + klo) = f2bf(f);
    }
  }

  float bb[8];
  #pragma unroll
  for (int ch = 0; ch < 8; ++ch) bb[ch] = b[ch * 16 + lr];

  // Direct A-fragment loads: row = w*16+lr, k = kt*32 + lg*8 .. +8.
  int row = w * 16 + lr;
  const float* hrow = src + (size_t)row * HID;
  float4 v0[8], v1[8];
  #pragma unroll
  for (int kt = 0; kt < 8; ++kt) {
    v0[kt] = *(const float4*)(hrow + kt * 32 + lg * 8);
    v1[kt] = *(const float4*)(hrow + kt * 32 + lg * 8 + 4);
  }
  short8 afr[8];
  #pragma unroll
  for (int kt = 0; kt < 8; ++kt) {
    short8 a;
    a[0] = (short)f2bf(v0[kt].x); a[1] = (short)f2bf(v0[kt].y);
    a[2] = (short)f2bf(v0[kt].z); a[3] = (short)f2bf(v0[kt].w);
    a[4] = (short)f2bf(v1[kt].x); a[5] = (short)f2bf(v1[kt].y);
    a[6] = (short)f2bf(v1[kt].z); a[7] = (short)f2bf(v1[kt].w);
    afr[kt] = a;
  }

  __syncthreads();   // wt staged

  f32x4 acc[8];
  #pragma unroll
  for (int ch = 0; ch < 8; ++ch) acc[ch] = (f32x4){0.f, 0.f, 0.f, 0.f};
  #pragma unroll
  for (int ch = 0; ch < 8; ++ch) {
    int ncol = ch * 16 + lr;
    #pragma unroll
    for (int kt = 0; kt < 8; ++kt) {
      int g = kt * 4 + lg;
      short8 bf = *(const short8*)(wt + ncol * 512 + ((g ^ (ncol & 31)) << 4));
      acc[ch] = __builtin_amdgcn_mfma_f32_16x16x32_bf16(afr[kt], bf, acc[ch], 0, 0, 0);
    }
  }

  // Epilogue: rows w*16 + lg*4 + r, cols ch*16 + lr.
  #pragma unroll
  for (int r = 0; r < 4; ++r) {
    float v[8];
    float ss = 0.f;
    #pragma unroll
    for (int ch = 0; ch < 8; ++ch) {
      v[ch] = fmaxf(acc[ch][r] + bb[ch], 0.f);
      ss += v[ch] * v[ch];
    }
    ss += __shfl_xor(ss, 1, 64);
    ss += __shfl_xor(ss, 2, 64);
    ss += __shfl_xor(ss, 4, 64);
    ss += __shfl_xor(ss, 8, 64);
    float rn = rsqrtf(ss) * scale;
    int orow = w * 16 + lg * 4 + r;
    float vf[8];
    #pragma unroll
    for (int ch = 0; ch < 8; ++ch) {
      vf[ch] = v[ch] * rn;
      dst[(size_t)orow * MI + ch * 16 + lr] = f2bf(vf[ch]);
    }
    #pragma unroll
    for (int ch = 0; ch < 8; ch += 2) {
      int pk = __builtin_amdgcn_cvt_pk_fp8_f32(vf[ch], vf[ch + 1], 0, false);
      dst8[(size_t)orow * MI + ch * 16 + lr] = (uchar_t)(pk & 0xff);
      dst8[(size_t)orow * MI + (ch + 1) * 16 + lr] = (uchar_t)((pk >> 8) & 0xff);
    }
  }
}

// ---------------------------------------------------------------------------
// Kernel 2: sim sweep (fp8 operands) + fused edge phase (bf16).
// r17 ledger: sim 89.5us ~= serial pipe sum (MFMA 33 + VALU 34 + LDS 13);
// overlap floor ~35us; only mechanism left is cross-block phase diversity,
// stuck at 2 blocks/CU since r5. fp8 halved fragment state (afr 32 VGPR,
// st 8), so ~124 total regs now plausibly fit the 128 = 512/4 boundary.
// THIS ROUND: __launch_bounds__(256, 4) pins the allocator at 128 total
// -> 4 waves/SIMD -> FOUR 256-thread blocks/CU (LDS: 4 x 36.8 = 147 <= 160
// KB). Sentinels: WRITE_SIZE ~10.75 MB (spill -> revert, r2/r4 signature);
// occupancy 20.7 -> 35-45% = pass.
// Block = 256 threads (4 waves x 64 rows) x 1024 cols; grid (16, 64).
// ---------------------------------------------------------------------------
__global__ __launch_bounds__(256, 4) void sim_kernel(
    const uchar_t* __restrict__ p1f8, const uchar_t* __restrict__ p2f8,
    const ushort_t* __restrict__ p1b, const ushort_t* __restrict__ p2b,
    float* __restrict__ rowsum, float* __restrict__ colsum,
    const int* __restrict__ pos_row, const int* __restrict__ pos_col,
    float* __restrict__ psum1, float* __restrict__ psum2,
    float* __restrict__ srow1, float* __restrict__ srow2,
    float* __restrict__ cntb, int E)
{
  __shared__ __align__(16) unsigned char ldsB[32768];   // 4 x 8 KB quad-buf
  __shared__ float colacc[1024];                        // 4 KB
  int t = threadIdx.x;                     // 0..255
  int lane = t & 63, w = t >> 6;           // 4 waves
  int lr = lane & 15, lg = lane >> 4;
  int rowbase = blockIdx.y * 256 + w * 64;   // wave owns 64 fixed rows
  int jbase = blockIdx.x * 1024;             // block owns 1024 cols

  // Staging: 2 granules of 16B per thread per tile (512 granules total).
  // granule t -> col t>>3 (0..31), slot t&7; granule t+256 -> col 32+(t>>3).
  uint4 st0, st1;
  int gs = t & 7, c0 = t >> 3;
  int sw = (gs ^ (c0 & 7)) << 4;           // same for c0 and c0+32

  auto load_stage = [&](int jt) {
    int j0 = jbase + jt * 64;
    const uchar_t* base = p2f8 + (size_t)(j0 + c0) * MI + (gs << 4);
    st0 = *(const uint4*)(base);
    st1 = *(const uint4*)(base + 32 * MI);
  };
  auto write_stage = [&](int buf) {
    unsigned char* base = ldsB + buf * 8192 + c0 * 128 + sw;
    *(uint4*)(base)            = st0;
    *(uint4*)(base + 32 * 128) = st1;
  };

  load_stage(0);

  // A frags: 64 rows x K=128 in fp8, 8 bytes (1 long) per fragment.
  long afr8[4][4];
  #pragma unroll
  for (int rt = 0; rt < 4; ++rt)
    #pragma unroll
    for (int kt = 0; kt < 4; ++kt)
      afr8[rt][kt] = *(const long*)(p1f8 + (size_t)(rowbase + rt * 16 + lr) * MI + kt * 32 + lg * 8);

  colacc[t] = 0.f;
  colacc[256 + t] = 0.f;
  colacc[512 + t] = 0.f;
  colacc[768 + t] = 0.f;

  f32x2 rs2[4][2];
  #pragma unroll
  for (int rt = 0; rt < 4; ++rt) {
    rs2[rt][0] = (f32x2){0.f, 0.f};
    rs2[rt][1] = (f32x2){0.f, 0.f};
  }

  // Prologue: stage tiles 0 and 1 (sequential, st regs reused).
  write_stage(0);
  load_stage(1);
  write_stage(1);
  __syncthreads();         // tiles 0,1 staged; colacc zeroed

  auto compute_tile = [&](int jt, const unsigned char* B) {
    #pragma unroll
    for (int ch = 0; ch < 4; ++ch) {
      f32x4 acc[4];
      #pragma unroll
      for (int rt = 0; rt < 4; ++rt) acc[rt] = (f32x4){0.f, 0.f, 0.f, 0.f};
      #pragma unroll
      for (int kt = 0; kt < 4; ++kt) {
        int ncol = ch * 16 + lr;
        int g = kt * 4 + lg;
        long bf8 = *(const long*)(B + ncol * 128 + (((g >> 1) ^ (ncol & 7)) << 4) + ((g & 1) << 3));
        #pragma unroll
        for (int rt = 0; rt < 4; ++rt)
          acc[rt] = __builtin_amdgcn_mfma_f32_16x16x32_fp8_fp8(afr8[rt][kt], bf8, acc[rt], 0, 0, 0);
      }
      // D layout: col = ch*16 + lr, row = rt*16 + lg*4 + reg.
      f32x2 cs2 = (f32x2){0.f, 0.f};
      #pragma unroll
      for (int rt = 0; rt < 4; ++rt) {
        f32x2 e01, e23;
        e01[0] = __builtin_amdgcn_exp2f(acc[rt][0]);
        e01[1] = __builtin_amdgcn_exp2f(acc[rt][1]);
        e23[0] = __builtin_amdgcn_exp2f(acc[rt][2]);
        e23[1] = __builtin_amdgcn_exp2f(acc[rt][3]);
        rs2[rt][0] += e01;
        rs2[rt][1] += e23;
        cs2 += e01;
        cs2 += e23;
      }
      float csum = cs2[0] + cs2[1];
      csum += __shfl_xor(csum, 16, 64);
      csum += __shfl_xor(csum, 32, 64);
      if (lg == 0) atomicAdd(&colacc[jt * 64 + ch * 16 + lr], csum);
    }
  };

  // Main loop: 8 iterations, 2 tiles + ONE barrier each (r14 schedule).
  for (int it = 0; it < 8; ++it) {
    int t0 = 2 * it, t1 = 2 * it + 1;
    const unsigned char* B0 = ldsB + (t0 & 3) * 8192;
    const unsigned char* B1 = ldsB + (t1 & 3) * 8192;
    if (it < 7) load_stage(t0 + 2);
    compute_tile(t0, B0);
    if (it < 7) {
      write_stage((t0 + 2) & 3);               // vmcnt drain covered by t0
      load_stage(t0 + 3);
    }
    compute_tile(t1, B1);
    if (it < 7) write_stage((t0 + 3) & 3);     // vmcnt drain covered by t1
    __syncthreads();   // one barrier per 2 tiles
  }

  // Row flush: butterfly over the 16 lr-lanes, one global atomic per row.
  #pragma unroll
  for (int rt = 0; rt < 4; ++rt)
    #pragma unroll
    for (int j = 0; j < 2; ++j)
      #pragma unroll
      for (int s = 0; s < 2; ++s) {
        float v = rs2[rt][j][s];
        v += __shfl_xor(v, 1, 64);
        v += __shfl_xor(v, 2, 64);
        v += __shfl_xor(v, 4, 64);
        v += __shfl_xor(v, 8, 64);
        if (lr == 0) atomicAdd(&rowsum[rowbase + rt * 16 + lg * 4 + j * 2 + s], v);
      }

  // Col flush: one global atomic per owned col.
  atomicAdd(&colsum[jbase + t], colacc[t]);
  atomicAdd(&colsum[jbase + 256 + t], colacc[256 + t]);
  atomicAdd(&colsum[jbase + 512 + t], colacc[512 + t]);
  atomicAdd(&colsum[jbase + 768 + t], colacc[768 + t]);

  // ---- Fused edge phase (bf16 operands, unchanged). ----
  {
    int eb = blockIdx.y * gridDim.x + blockIdx.x;   // 0..1023
    int e = eb * 64 + (t >> 2), q = t & 3;
    if (e < E) {
      int r = pos_row[e], c = pos_col[e];
      const uint4* a1 = (const uint4*)(p1b + (size_t)r * MI) + q * 4;
      const uint4* b1 = (const uint4*)(p2b + (size_t)c * MI) + q * 4;
      const uint4* a2 = (const uint4*)(p1b + (size_t)c * MI) + q * 4;
      const uint4* b2 = (const uint4*)(p2b + (size_t)r * MI) + q * 4;
      float d1 = 0.f, d2 = 0.f;
      #pragma unroll
      for (int it = 0; it < 4; ++it) {
        uint4 x = a1[it], y = b1[it];
        d1 += bflo(x.x) * bflo(y.x) + bfhi(x.x) * bfhi(y.x);
        d1 += bflo(x.y) * bflo(y.y) + bfhi(x.y) * bfhi(y.y);
        d1 += bflo(x.z) * bflo(y.z) + bfhi(x.z) * bfhi(y.z);
        d1 += bflo(x.w) * bflo(y.w) + bfhi(x.w) * bfhi(y.w);
        uint4 u = a2[it], v = b2[it];
        d2 += bflo(u.x) * bflo(v.x) + bfhi(u.x) * bfhi(v.x);
        d2 += bflo(u.y) * bflo(v.y) + bfhi(u.y) * bfhi(v.y);
        d2 += bflo(u.z) * bflo(v.z) + bfhi(u.z) * bfhi(v.z);
        d2 += bflo(u.w) * bflo(v.w) + bfhi(u.w) * bfhi(v.w);
      }
      d1 += __shfl_xor(d1, 1, 64);
      d1 += __shfl_xor(d1, 2, 64);
      d2 += __shfl_xor(d2, 1, 64);
      d2 += __shfl_xor(d2, 2, 64);
      if (q == 0) {
        float e1 = __builtin_amdgcn_exp2f(d1);
        float e2 = __builtin_amdgcn_exp2f(d2);
        atomicAdd(&psum1[r], e1);
        atomicAdd(&srow1[r], d1 * LN2F);
        atomicAdd(&psum2[r], e2);
        atomicAdd(&srow2[r], d2 * LN2F);
        atomicAdd(&cntb[r], 1.0f);
      }
    }
  }
}

// ---------------------------------------------------------------------------
// Kernel 3: loss contribution per row, atomicAdd into out[0] (pre-zeroed).
// ---------------------------------------------------------------------------
__global__ __launch_bounds__(256) void finalize_kernel(
    const float* __restrict__ rowsum, const float* __restrict__ colsum,
    const float* __restrict__ psum1, const float* __restrict__ psum2,
    const float* __restrict__ srow1, const float* __restrict__ srow2,
    const float* __restrict__ cntb, float* __restrict__ out, int n)
{
  __shared__ float sred[4];
  int r = blockIdx.x * 256 + threadIdx.x;
  float local = 0.f;
  if (r < n) {
    float inv = 1.0f / cntb[r];
    float d1 = rowsum[r] - psum1[r];
    float d2 = colsum[r] - psum2[r];
    local = srow1[r] * inv - __builtin_amdgcn_logf(d1) * LN2F
          + srow2[r] * inv - __builtin_amdgcn_logf(d2) * LN2F;
  }
  #pragma unroll
  for (int m = 1; m <= 32; m <<= 1) local += __shfl_xor(local, m, 64);
  int lane = threadIdx.x & 63, wv = threadIdx.x >> 6;
  if (lane == 0) sred[wv] = local;
  __syncthreads();
  if (threadIdx.x == 0) {
    float tot = sred[0] + sred[1] + sred[2] + sred[3];
    atomicAdd(out, -tot / (2.0f * n));
  }
}

extern "C" void kernel_launch(void* const* d_in, const int* in_sizes, int n_in,
                              void* d_out, int out_size, void* d_ws, size_t ws_size,
                              hipStream_t stream)
{
  const float* h1 = (const float*)d_in[0];
  const float* h2 = (const float*)d_in[1];
  const float* W  = (const float*)d_in[2];
  const float* b  = (const float*)d_in[3];
  const int* pos_row = (const int*)d_in[4];
  const int* pos_col = (const int*)d_in[5];
  int n = in_sizes[0] / HID;      // 16384
  int E = in_sizes[4];            // 65536
  float* out = (float*)d_out;

  char* ws = (char*)d_ws;
  ushort_t* p1b = (ushort_t*)ws;                       // n*128 bf16 = 4 MB
  ushort_t* p2b = p1b + (size_t)n * MI;                // 4 MB
  float* fbase  = (float*)(ws + (size_t)2 * n * MI * sizeof(ushort_t));
  float* rowsum = fbase;
  float* colsum = rowsum + n;
  float* psum1  = colsum + n;
  float* psum2  = psum1 + n;
  float* srow1  = psum2 + n;
  float* srow2  = srow1 + n;
  float* cntb   = srow2 + n;
  uchar_t* p1f8 = (uchar_t*)(cntb + n);                // n*128 fp8 = 2 MB
  uchar_t* p2f8 = p1f8 + (size_t)n * MI;               // 2 MB

  int nz = 7 * n;
  proj_kernel<<<2 * n / 64, 256, 0, stream>>>(h1, h2, W, b, p1b, p2b,
                                              p1f8, p2f8, fbase, nz, out, n);
  dim3 g2(n / 1024, n / 256);     // (colgroups, rowgroups) = (16, 64)
  sim_kernel<<<g2, 256, 0, stream>>>(p1f8, p2f8, p1b, p2b, rowsum, colsum,
                                     pos_row, pos_col, psum1, psum2,
                                     srow1, srow2, cntb, E);
  finalize_kernel<<<(n + 255) / 256, 256, 0, stream>>>(rowsum, colsum, psum1, psum2,
                                                       srow1, srow2, cntb, out, n);
}

// Round 19
// 179.725 us; speedup vs baseline: 2.8294x; 2.8294x over previous
//
#include <hip/hip_runtime.h>

typedef unsigned short ushort_t;
typedef unsigned char uchar_t;
typedef unsigned int uint32;
typedef __attribute__((ext_vector_type(8))) short short8;
typedef __attribute__((ext_vector_type(4))) float f32x4;
typedef __attribute__((ext_vector_type(2))) float f32x2;

#define HID 256
#define MI 128
// p1 is pre-scaled by ALPHA = 2/ln2, so sim MFMA output = cos*2/ln2 and
// exp(cos/T) = exp2(acc) directly. Edge ln-logit: s = 2*cos = d * ln2.
#define ALPHA 2.8853900817779268f
#define LN2F 0.69314718055994531f

__device__ __forceinline__ float bflo(uint32 u) { return __uint_as_float(u << 16); }
__device__ __forceinline__ float bfhi(uint32 u) { return __uint_as_float(u & 0xffff0000u); }
__device__ __forceinline__ ushort_t f2bf(float f) {
  uint32 u = __float_as_uint(f);
  u += 0x7fffu + ((u >> 16) & 1u);   // RNE
  return (ushort_t)(u >> 16);
}

// ---------------------------------------------------------------------------
// Kernel 1 (prep fused, r13): p = l2norm(relu(h @ W + b)).
// Outputs BOTH bf16 (p1b/p2b, edge logits) and fp8 e4m3 (p1f8/p2f8, sim
// row/col sums). W staged to 64 KB LDS bf16 W^T. UNCHANGED from r15/r17.
// ---------------------------------------------------------------------------
__global__ __launch_bounds__(256) void proj_kernel(
    const float* __restrict__ h1, const float* __restrict__ h2,
    const float* __restrict__ W, const float* __restrict__ b,
    ushort_t* __restrict__ p1b, ushort_t* __restrict__ p2b,
    uchar_t* __restrict__ p1f8, uchar_t* __restrict__ p2f8,
    float* __restrict__ fbase, int nz, float* __restrict__ out, int n)
{
  __shared__ __align__(16) unsigned char wt[65536];   // 128 x 256 bf16 W^T
  int t = threadIdx.x;
  int lane = t & 63, w = t >> 6;
  int lr = lane & 15, lg = lane >> 4;
  long R0 = (long)blockIdx.x * 64;
  const float* src = (R0 < n) ? (h1 + R0 * HID) : (h2 + (R0 - n) * HID);
  ushort_t* dst = (R0 < n) ? (p1b + R0 * MI) : (p2b + (R0 - n) * MI);
  uchar_t* dst8 = (R0 < n) ? (p1f8 + R0 * MI) : (p2f8 + (R0 - n) * MI);
  float scale = (R0 < n) ? ALPHA : 1.0f;

  // ---- fbase zero slice (prep work, disjoint per block) ----
  {
    int base = blockIdx.x * 224;        // 512 * 224 = 114688 = 7n
    if (t < 224 && base + t < nz) fbase[base + t] = 0.f;
    if (blockIdx.x == 0 && t == 0) out[0] = 0.f;
  }

  // ---- Stage W -> LDS W^T (bf16, swizzled). 32 float4 per thread. ----
  #pragma unroll
  for (int i = 0; i < 32; ++i) {
    int idx4 = i * 1024 + t * 4;        // 4 consecutive ncol, same k
    float4 v = *(const float4*)(W + idx4);
    int k = idx4 >> 7, nc0 = idx4 & 127;
    int g = k >> 3, klo = (k & 7) * 2;
    #pragma unroll
    for (int j = 0; j < 4; ++j) {
      int nc = nc0 + j;
      float f = (j == 0) ? v.x : (j == 1) ? v.y : (j == 2) ? v.z : v.w;
      *(ushort_t*)(wt + nc * 512 + ((g ^ (nc & 31)) << 4) + klo) = f2bf(f);
    }
  }

  float bb[8];
  #pragma unroll
  for (int ch = 0; ch < 8; ++ch) bb[ch] = b[ch * 16 + lr];

  // Direct A-fragment loads: row = w*16+lr, k = kt*32 + lg*8 .. +8.
  int row = w * 16 + lr;
  const float* hrow = src + (size_t)row * HID;
  float4 v0[8], v1[8];
  #pragma unroll
  for (int kt = 0; kt < 8; ++kt) {
    v0[kt] = *(const float4*)(hrow + kt * 32 + lg * 8);
    v1[kt] = *(const float4*)(hrow + kt * 32 + lg * 8 + 4);
  }
  short8 afr[8];
  #pragma unroll
  for (int kt = 0; kt < 8; ++kt) {
    short8 a;
    a[0] = (short)f2bf(v0[kt].x); a[1] = (short)f2bf(v0[kt].y);
    a[2] = (short)f2bf(v0[kt].z); a[3] = (short)f2bf(v0[kt].w);
    a[4] = (short)f2bf(v1[kt].x); a[5] = (short)f2bf(v1[kt].y);
    a[6] = (short)f2bf(v1[kt].z); a[7] = (short)f2bf(v1[kt].w);
    afr[kt] = a;
  }

  __syncthreads();   // wt staged

  f32x4 acc[8];
  #pragma unroll
  for (int ch = 0; ch < 8; ++ch) acc[ch] = (f32x4){0.f, 0.f, 0.f, 0.f};
  #pragma unroll
  for (int ch = 0; ch < 8; ++ch) {
    int ncol = ch * 16 + lr;
    #pragma unroll
    for (int kt = 0; kt < 8; ++kt) {
      int g = kt * 4 + lg;
      short8 bf = *(const short8*)(wt + ncol * 512 + ((g ^ (ncol & 31)) << 4));
      acc[ch] = __builtin_amdgcn_mfma_f32_16x16x32_bf16(afr[kt], bf, acc[ch], 0, 0, 0);
    }
  }

  // Epilogue: rows w*16 + lg*4 + r, cols ch*16 + lr.
  #pragma unroll
  for (int r = 0; r < 4; ++r) {
    float v[8];
    float ss = 0.f;
    #pragma unroll
    for (int ch = 0; ch < 8; ++ch) {
      v[ch] = fmaxf(acc[ch][r] + bb[ch], 0.f);
      ss += v[ch] * v[ch];
    }
    ss += __shfl_xor(ss, 1, 64);
    ss += __shfl_xor(ss, 2, 64);
    ss += __shfl_xor(ss, 4, 64);
    ss += __shfl_xor(ss, 8, 64);
    float rn = rsqrtf(ss) * scale;
    int orow = w * 16 + lg * 4 + r;
    float vf[8];
    #pragma unroll
    for (int ch = 0; ch < 8; ++ch) {
      vf[ch] = v[ch] * rn;
      dst[(size_t)orow * MI + ch * 16 + lr] = f2bf(vf[ch]);
    }
    #pragma unroll
    for (int ch = 0; ch < 8; ch += 2) {
      int pk = __builtin_amdgcn_cvt_pk_fp8_f32(vf[ch], vf[ch + 1], 0, false);
      dst8[(size_t)orow * MI + ch * 16 + lr] = (uchar_t)(pk & 0xff);
      dst8[(size_t)orow * MI + (ch + 1) * 16 + lr] = (uchar_t)((pk >> 8) & 0xff);
    }
  }
}

// ---------------------------------------------------------------------------
// Kernel 2: sim sweep (fp8 operands) + fused edge phase (bf16).
// r18 POST-MORTEM: __launch_bounds__(256,4) spilled (VGPR 64, 1.3 GB
// scratch, sim 418us) — 4th data point pinning the register model:
// (.,2)->108 clean / (.,3)->84+spill / (.,4)->64+spill. 2 blocks/CU is a
// hard floor for this shape; occupancy direction CLOSED. Occupancy did hit
// 45% (mechanism exists) but unaffordable. REVERTED to r17 exactly
// (best verified: sim 89.5us, total 179.9us).
// Block = 256 threads (4 waves x 64 rows) x 1024 cols; grid (16, 64).
// ---------------------------------------------------------------------------
__global__ __launch_bounds__(256, 2) void sim_kernel(
    const uchar_t* __restrict__ p1f8, const uchar_t* __restrict__ p2f8,
    const ushort_t* __restrict__ p1b, const ushort_t* __restrict__ p2b,
    float* __restrict__ rowsum, float* __restrict__ colsum,
    const int* __restrict__ pos_row, const int* __restrict__ pos_col,
    float* __restrict__ psum1, float* __restrict__ psum2,
    float* __restrict__ srow1, float* __restrict__ srow2,
    float* __restrict__ cntb, int E)
{
  __shared__ __align__(16) unsigned char ldsB[32768];   // 4 x 8 KB quad-buf
  __shared__ float colacc[1024];                        // 4 KB
  int t = threadIdx.x;                     // 0..255
  int lane = t & 63, w = t >> 6;           // 4 waves
  int lr = lane & 15, lg = lane >> 4;
  int rowbase = blockIdx.y * 256 + w * 64;   // wave owns 64 fixed rows
  int jbase = blockIdx.x * 1024;             // block owns 1024 cols

  // Staging: 2 granules of 16B per thread per tile (512 granules total).
  // granule t -> col t>>3 (0..31), slot t&7; granule t+256 -> col 32+(t>>3).
  uint4 st0, st1;
  int gs = t & 7, c0 = t >> 3;
  int sw = (gs ^ (c0 & 7)) << 4;           // same for c0 and c0+32

  auto load_stage = [&](int jt) {
    int j0 = jbase + jt * 64;
    const uchar_t* base = p2f8 + (size_t)(j0 + c0) * MI + (gs << 4);
    st0 = *(const uint4*)(base);
    st1 = *(const uint4*)(base + 32 * MI);
  };
  auto write_stage = [&](int buf) {
    unsigned char* base = ldsB + buf * 8192 + c0 * 128 + sw;
    *(uint4*)(base)            = st0;
    *(uint4*)(base + 32 * 128) = st1;
  };

  load_stage(0);

  // A frags: 64 rows x K=128 in fp8, 8 bytes (1 long) per fragment.
  long afr8[4][4];
  #pragma unroll
  for (int rt = 0; rt < 4; ++rt)
    #pragma unroll
    for (int kt = 0; kt < 4; ++kt)
      afr8[rt][kt] = *(const long*)(p1f8 + (size_t)(rowbase + rt * 16 + lr) * MI + kt * 32 + lg * 8);

  colacc[t] = 0.f;
  colacc[256 + t] = 0.f;
  colacc[512 + t] = 0.f;
  colacc[768 + t] = 0.f;

  f32x2 rs2[4][2];
  #pragma unroll
  for (int rt = 0; rt < 4; ++rt) {
    rs2[rt][0] = (f32x2){0.f, 0.f};
    rs2[rt][1] = (f32x2){0.f, 0.f};
  }

  // Prologue: stage tiles 0 and 1 (sequential, st regs reused).
  write_stage(0);
  load_stage(1);
  write_stage(1);
  __syncthreads();         // tiles 0,1 staged; colacc zeroed

  auto compute_tile = [&](int jt, const unsigned char* B) {
    #pragma unroll
    for (int ch = 0; ch < 4; ++ch) {
      f32x4 acc[4];
      #pragma unroll
      for (int rt = 0; rt < 4; ++rt) acc[rt] = (f32x4){0.f, 0.f, 0.f, 0.f};
      #pragma unroll
      for (int kt = 0; kt < 4; ++kt) {
        int ncol = ch * 16 + lr;
        int g = kt * 4 + lg;
        long bf8 = *(const long*)(B + ncol * 128 + (((g >> 1) ^ (ncol & 7)) << 4) + ((g & 1) << 3));
        #pragma unroll
        for (int rt = 0; rt < 4; ++rt)
          acc[rt] = __builtin_amdgcn_mfma_f32_16x16x32_fp8_fp8(afr8[rt][kt], bf8, acc[rt], 0, 0, 0);
      }
      // D layout: col = ch*16 + lr, row = rt*16 + lg*4 + reg.
      f32x2 cs2 = (f32x2){0.f, 0.f};
      #pragma unroll
      for (int rt = 0; rt < 4; ++rt) {
        f32x2 e01, e23;
        e01[0] = __builtin_amdgcn_exp2f(acc[rt][0]);
        e01[1] = __builtin_amdgcn_exp2f(acc[rt][1]);
        e23[0] = __builtin_amdgcn_exp2f(acc[rt][2]);
        e23[1] = __builtin_amdgcn_exp2f(acc[rt][3]);
        rs2[rt][0] += e01;
        rs2[rt][1] += e23;
        cs2 += e01;
        cs2 += e23;
      }
      float csum = cs2[0] + cs2[1];
      csum += __shfl_xor(csum, 16, 64);
      csum += __shfl_xor(csum, 32, 64);
      if (lg == 0) atomicAdd(&colacc[jt * 64 + ch * 16 + lr], csum);
    }
  };

  // Main loop: 8 iterations, 2 tiles + ONE barrier each (r14 schedule).
  for (int it = 0; it < 8; ++it) {
    int t0 = 2 * it, t1 = 2 * it + 1;
    const unsigned char* B0 = ldsB + (t0 & 3) * 8192;
    const unsigned char* B1 = ldsB + (t1 & 3) * 8192;
    if (it < 7) load_stage(t0 + 2);
    compute_tile(t0, B0);
    if (it < 7) {
      write_stage((t0 + 2) & 3);               // vmcnt drain covered by t0
      load_stage(t0 + 3);
    }
    compute_tile(t1, B1);
    if (it < 7) write_stage((t0 + 3) & 3);     // vmcnt drain covered by t1
    __syncthreads();   // one barrier per 2 tiles
  }

  // Row flush: butterfly over the 16 lr-lanes, one global atomic per row.
  #pragma unroll
  for (int rt = 0; rt < 4; ++rt)
    #pragma unroll
    for (int j = 0; j < 2; ++j)
      #pragma unroll
      for (int s = 0; s < 2; ++s) {
        float v = rs2[rt][j][s];
        v += __shfl_xor(v, 1, 64);
        v += __shfl_xor(v, 2, 64);
        v += __shfl_xor(v, 4, 64);
        v += __shfl_xor(v, 8, 64);
        if (lr == 0) atomicAdd(&rowsum[rowbase + rt * 16 + lg * 4 + j * 2 + s], v);
      }

  // Col flush: one global atomic per owned col.
  atomicAdd(&colsum[jbase + t], colacc[t]);
  atomicAdd(&colsum[jbase + 256 + t], colacc[256 + t]);
  atomicAdd(&colsum[jbase + 512 + t], colacc[512 + t]);
  atomicAdd(&colsum[jbase + 768 + t], colacc[768 + t]);

  // ---- Fused edge phase (bf16 operands, unchanged). ----
  {
    int eb = blockIdx.y * gridDim.x + blockIdx.x;   // 0..1023
    int e = eb * 64 + (t >> 2), q = t & 3;
    if (e < E) {
      int r = pos_row[e], c = pos_col[e];
      const uint4* a1 = (const uint4*)(p1b + (size_t)r * MI) + q * 4;
      const uint4* b1 = (const uint4*)(p2b + (size_t)c * MI) + q * 4;
      const uint4* a2 = (const uint4*)(p1b + (size_t)c * MI) + q * 4;
      const uint4* b2 = (const uint4*)(p2b + (size_t)r * MI) + q * 4;
      float d1 = 0.f, d2 = 0.f;
      #pragma unroll
      for (int it = 0; it < 4; ++it) {
        uint4 x = a1[it], y = b1[it];
        d1 += bflo(x.x) * bflo(y.x) + bfhi(x.x) * bfhi(y.x);
        d1 += bflo(x.y) * bflo(y.y) + bfhi(x.y) * bfhi(y.y);
        d1 += bflo(x.z) * bflo(y.z) + bfhi(x.z) * bfhi(y.z);
        d1 += bflo(x.w) * bflo(y.w) + bfhi(x.w) * bfhi(y.w);
        uint4 u = a2[it], v = b2[it];
        d2 += bflo(u.x) * bflo(v.x) + bfhi(u.x) * bfhi(v.x);
        d2 += bflo(u.y) * bflo(v.y) + bfhi(u.y) * bfhi(v.y);
        d2 += bflo(u.z) * bflo(v.z) + bfhi(u.z) * bfhi(v.z);
        d2 += bflo(u.w) * bflo(v.w) + bfhi(u.w) * bfhi(v.w);
      }
      d1 += __shfl_xor(d1, 1, 64);
      d1 += __shfl_xor(d1, 2, 64);
      d2 += __shfl_xor(d2, 1, 64);
      d2 += __shfl_xor(d2, 2, 64);
      if (q == 0) {
        float e1 = __builtin_amdgcn_exp2f(d1);
        float e2 = __builtin_amdgcn_exp2f(d2);
        atomicAdd(&psum1[r], e1);
        atomicAdd(&srow1[r], d1 * LN2F);
        atomicAdd(&psum2[r], e2);
        atomicAdd(&srow2[r], d2 * LN2F);
        atomicAdd(&cntb[r], 1.0f);
      }
    }
  }
}

// ---------------------------------------------------------------------------
// Kernel 3: loss contribution per row, atomicAdd into out[0] (pre-zeroed).
// ---------------------------------------------------------------------------
__global__ __launch_bounds__(256) void finalize_kernel(
    const float* __restrict__ rowsum, const float* __restrict__ colsum,
    const float* __restrict__ psum1, const float* __restrict__ psum2,
    const float* __restrict__ srow1, const float* __restrict__ srow2,
    const float* __restrict__ cntb, float* __restrict__ out, int n)
{
  __shared__ float sred[4];
  int r = blockIdx.x * 256 + threadIdx.x;
  float local = 0.f;
  if (r < n) {
    float inv = 1.0f / cntb[r];
    float d1 = rowsum[r] - psum1[r];
    float d2 = colsum[r] - psum2[r];
    local = srow1[r] * inv - __builtin_amdgcn_logf(d1) * LN2F
          + srow2[r] * inv - __builtin_amdgcn_logf(d2) * LN2F;
  }
  #pragma unroll
  for (int m = 1; m <= 32; m <<= 1) local += __shfl_xor(local, m, 64);
  int lane = threadIdx.x & 63, wv = threadIdx.x >> 6;
  if (lane == 0) sred[wv] = local;
  __syncthreads();
  if (threadIdx.x == 0) {
    float tot = sred[0] + sred[1] + sred[2] + sred[3];
    atomicAdd(out, -tot / (2.0f * n));
  }
}

extern "C" void kernel_launch(void* const* d_in, const int* in_sizes, int n_in,
                              void* d_out, int out_size, void* d_ws, size_t ws_size,
                              hipStream_t stream)
{
  const float* h1 = (const float*)d_in[0];
  const float* h2 = (const float*)d_in[1];
  const float* W  = (const float*)d_in[2];
  const float* b  = (const float*)d_in[3];
  const int* pos_row = (const int*)d_in[4];
  const int* pos_col = (const int*)d_in[5];
  int n = in_sizes[0] / HID;      // 16384
  int E = in_sizes[4];            // 65536
  float* out = (float*)d_out;

  char* ws = (char*)d_ws;
  ushort_t* p1b = (ushort_t*)ws;                       // n*128 bf16 = 4 MB
  ushort_t* p2b = p1b + (size_t)n * MI;                // 4 MB
  float* fbase  = (float*)(ws + (size_t)2 * n * MI * sizeof(ushort_t));
  float* rowsum = fbase;
  float* colsum = rowsum + n;
  float* psum1  = colsum + n;
  float* psum2  = psum1 + n;
  float* srow1  = psum2 + n;
  float* srow2  = srow1 + n;
  float* cntb   = srow2 + n;
  uchar_t* p1f8 = (uchar_t*)(cntb + n);                // n*128 fp8 = 2 MB
  uchar_t* p2f8 = p1f8 + (size_t)n * MI;               // 2 MB

  int nz = 7 * n;
  proj_kernel<<<2 * n / 64, 256, 0, stream>>>(h1, h2, W, b, p1b, p2b,
                                              p1f8, p2f8, fbase, nz, out, n);
  dim3 g2(n / 1024, n / 256);     // (colgroups, rowgroups) = (16, 64)
  sim_kernel<<<g2, 256, 0, stream>>>(p1f8, p2f8, p1b, p2b, rowsum, colsum,
                                     pos_row, pos_col, psum1, psum2,
                                     srow1, srow2, cntb, E);
  finalize_kernel<<<(n + 255) / 256, 256, 0, stream>>>(rowsum, colsum, psum1, psum2,
                                                       srow1, srow2, cntb, out, n);
}